// Round 4
// baseline (63.718 us; speedup 1.0000x reference)
//
#include <hip/hip_runtime.h>

// SGC: out = A^K (x w) + b  (rank-1 projection first), A = D^-1/2 (Adj+I) D^-1/2, K=2.
// Per-edge device atomics measured at ~16.7 G/s (48 us/pass) on gfx950 -> eliminated by
// binning edges into 1024-node destination chunks (k_bin, LDS histograms + ~22K
// reservation atomics), then LDS-accumulated hops (ds_add_f32) + slab reduce.
// R3 lesson: hipMemsetAsync(256B) inside the graph = 40 us fillBufferAligned dispatch;
// replaced with a 1-block k_zero kernel.

#define D_FEAT    128
#define CHUNK_LG  10
#define CHUNK     1024
#define NSLAB     16
#define RECS      7           // edges per thread in k_bin; stripe = RECS*256
#define MAXC      64

__global__ void k_zero(int* __restrict__ cnt) {
    cnt[threadIdx.x] = 0;      // <<<1, 64>>>
}

// Pack edges into per-chunk buckets: rec = (dst_local<<16) | src  (ids < 65536).
__global__ void k_bin(const int* __restrict__ src, const int* __restrict__ dst,
                      int E, int nchunks, int cap,
                      int* __restrict__ cnt, unsigned int* __restrict__ binned) {
    __shared__ int hist[MAXC], base[MAXC], cur[MAXC];
    int t = threadIdx.x;
    if (t < nchunks) { hist[t] = 0; cur[t] = 0; }
    __syncthreads();
    int e0 = blockIdx.x * (RECS * 256);
    unsigned int rec[RECS];
    int ch[RECS];
    #pragma unroll
    for (int k = 0; k < RECS; k++) {
        int e = e0 + k * 256 + t;
        if (e < E) {
            int s = src[e], d = dst[e];
            ch[k]  = d >> CHUNK_LG;
            rec[k] = ((unsigned)(d & (CHUNK - 1)) << 16) | (unsigned)s;
            atomicAdd(&hist[ch[k]], 1);
        } else ch[k] = -1;
    }
    __syncthreads();
    if (t < nchunks) base[t] = atomicAdd(&cnt[t], hist[t]);   // few device atomics
    __syncthreads();
    #pragma unroll
    for (int k = 0; k < RECS; k++) {
        if (ch[k] >= 0) {
            int slot = base[ch[k]] + atomicAdd(&cur[ch[k]], 1);
            if (slot < cap) binned[(size_t)ch[k] * cap + slot] = rec[k];
        }
    }
}

// One chunk per c, NSLAB slabs; LDS fp32 accumulation; coalesced partial writes.
// MODE 0: count (value 1.0); MODE 1: sum val[src].
template <int MODE>
__global__ void k_hop(const unsigned int* __restrict__ binned, const int* __restrict__ cnt,
                      int cap, const float* __restrict__ val, float* __restrict__ partial) {
    __shared__ float acc[CHUNK];
    int c = blockIdx.x >> 4;          // / NSLAB
    int m = blockIdx.x & (NSLAB - 1);
    int t = threadIdx.x;
    #pragma unroll
    for (int k = 0; k < CHUNK / 256; k++) acc[t + k * 256] = 0.f;
    __syncthreads();
    int nc = cnt[c]; if (nc > cap) nc = cap;
    const unsigned int* bb = binned + (size_t)c * cap;
    for (int e = m * 256 + t; e < nc; e += NSLAB * 256) {
        unsigned int r = bb[e];
        float v = (MODE == 0) ? 1.0f : val[r & 0xFFFFu];
        atomicAdd(&acc[r >> 16], v);           // ds_add_f32
    }
    __syncthreads();
    float* pp = partial + ((size_t)(c * NSLAB + m) << CHUNK_LG);
    #pragma unroll
    for (int k = 0; k < CHUNK / 256; k++) pp[t + k * 256] = acc[t + k * 256];
}

// y[i] = x_i . w   (one wave per node, float2 loads)
__global__ void k_dot(const float* __restrict__ x, const float* __restrict__ W,
                      float* __restrict__ y, int n) {
    int wid  = (blockIdx.x * blockDim.x + threadIdx.x) >> 6;
    int lane = threadIdx.x & 63;
    if (wid >= n) return;
    const float2* xr = (const float2*)(x + (size_t)wid * D_FEAT);
    const float2* wr = (const float2*)W;
    float2 xv = xr[lane];
    float2 wv = wr[lane];
    float v = xv.x * wv.x + xv.y * wv.y;
    #pragma unroll
    for (int off = 32; off; off >>= 1) v += __shfl_xor(v, off);
    if (lane == 0) y[wid] = v;
}

// Sum the NSLAB partial slabs per node, then variant-specific epilogue.
// V0: dis=rsqrt(deg+1), u=dis*y      V1: u2=dis^2*(s+u)      V2: out=dis*(s+u2)+b
template <int V>
__global__ void k_reduce(const float* __restrict__ partial, int n,
                         const float* __restrict__ y, float* __restrict__ dis,
                         float* __restrict__ u, float* __restrict__ u2,
                         const float* __restrict__ b, float* __restrict__ out) {
    int i = blockIdx.x * blockDim.x + threadIdx.x;
    if (i >= n) return;
    int c = i >> CHUNK_LG, l = i & (CHUNK - 1);
    const float* pp = partial + ((size_t)(c * NSLAB) << CHUNK_LG) + l;
    float s = 0.f;
    #pragma unroll
    for (int m = 0; m < NSLAB; m++) s += pp[m << CHUNK_LG];
    if (V == 0) { float d = rsqrtf(s + 1.0f); dis[i] = d; u[i] = d * y[i]; }
    if (V == 1) { float d = dis[i]; u2[i] = d * d * (s + u[i]); }
    if (V == 2) { out[i] = dis[i] * (s + u2[i]) + b[0]; }
}

// ---------------- fallback (atomic) path, known-correct ----------------

__global__ void k_deg(const int* __restrict__ dst, int* __restrict__ deg, int E) {
    int e = blockIdx.x * blockDim.x + threadIdx.x;
    if (e < E) atomicAdd(&deg[dst[e]], 1);
}
__global__ void k_init(const float* __restrict__ x, const float* __restrict__ W,
                       const int* __restrict__ deg, float* __restrict__ dis,
                       float* __restrict__ u, int n) {
    int wid  = (blockIdx.x * blockDim.x + threadIdx.x) >> 6;
    int lane = threadIdx.x & 63;
    if (wid >= n) return;
    const float2* xr = (const float2*)(x + (size_t)wid * D_FEAT);
    const float2* wr = (const float2*)W;
    float2 xv = xr[lane];
    float2 wv = wr[lane];
    float v = xv.x * wv.x + xv.y * wv.y;
    #pragma unroll
    for (int off = 32; off; off >>= 1) v += __shfl_xor(v, off);
    if (lane == 0) { float di = rsqrtf((float)(deg[wid] + 1)); dis[wid] = di; u[wid] = di * v; }
}
__global__ void k_scatter(const int* __restrict__ src, const int* __restrict__ dst,
                          const float* __restrict__ u, float* __restrict__ s, int E) {
    int e = blockIdx.x * blockDim.x + threadIdx.x;
    if (e < E) unsafeAtomicAdd(&s[dst[e]], u[src[e]]);
}
__global__ void k_update(const float* __restrict__ dis, const float* __restrict__ s,
                         float* __restrict__ u, int n) {
    int i = blockIdx.x * blockDim.x + threadIdx.x;
    if (i < n) { float di = dis[i]; u[i] = di * di * (s[i] + u[i]); }
}
__global__ void k_final(const float* __restrict__ dis, const float* __restrict__ s,
                        const float* __restrict__ u, const float* __restrict__ b,
                        float* __restrict__ out, int n) {
    int i = blockIdx.x * blockDim.x + threadIdx.x;
    if (i < n) out[i] = dis[i] * (s[i] + u[i]) + b[0];
}

extern "C" void kernel_launch(void* const* d_in, const int* in_sizes, int n_in,
                              void* d_out, int out_size, void* d_ws, size_t ws_size,
                              hipStream_t stream) {
    const float* x  = (const float*)d_in[0];
    const int*   ei = (const int*)d_in[1];   // [2,E]; row0=src, row1=dst
    const float* W  = (const float*)d_in[2];
    const float* b  = (const float*)d_in[3];
    float* out = (float*)d_out;

    const int n = out_size;           // 50000
    const int E = in_sizes[1] / 2;    // 800000
    const int* src = ei;
    const int* dst = ei + E;

    const int TB = 256;
    const int C  = (n + CHUNK - 1) >> CHUNK_LG;                 // 49
    const int cap = (int)((long long)E * 5 / (4 * C)) + 512;    // ~25% headroom

    size_t need = 64 * 4 + (size_t)C * cap * 4 + (size_t)C * NSLAB * CHUNK * 4 + (size_t)4 * n * 4;

    if (n <= 65536 && C <= MAXC && ws_size >= need) {
        int*          cnt    = (int*)d_ws;
        unsigned int* binned = (unsigned int*)(cnt + 64);
        float*        part   = (float*)(binned + (size_t)C * cap);
        float*        y      = part + (size_t)C * NSLAB * CHUNK;
        float*        dis    = y + n;
        float*        u      = dis + n;
        float*        u2     = u + n;

        const int binBlocks = (E + RECS * 256 - 1) / (RECS * 256);
        const int hopBlocks = C * NSLAB;
        const int nb        = (n + TB - 1) / TB;
        const int dotBlocks = ((size_t)n * 64 + TB - 1) / TB;

        k_zero<<<1, 64, 0, stream>>>(cnt);
        k_bin<<<binBlocks, TB, 0, stream>>>(src, dst, E, C, cap, cnt, binned);
        k_dot<<<dotBlocks, TB, 0, stream>>>(x, W, y, n);

        k_hop<0><<<hopBlocks, TB, 0, stream>>>(binned, cnt, cap, y, part);       // degree
        k_reduce<0><<<nb, TB, 0, stream>>>(part, n, y, dis, u, u2, b, out);

        k_hop<1><<<hopBlocks, TB, 0, stream>>>(binned, cnt, cap, u, part);       // hop 1
        k_reduce<1><<<nb, TB, 0, stream>>>(part, n, y, dis, u, u2, b, out);

        k_hop<1><<<hopBlocks, TB, 0, stream>>>(binned, cnt, cap, u2, part);      // hop 2
        k_reduce<2><<<nb, TB, 0, stream>>>(part, n, y, dis, u, u2, b, out);
    } else {
        int*   deg = (int*)d_ws;
        float* s1  = (float*)d_ws + n;
        float* s2  = s1 + n;
        float* dis = s2 + n;
        float* u   = dis + n;
        const int eb = (E + TB - 1) / TB;
        const int nb = (n + TB - 1) / TB;
        const int ib = ((size_t)n * 64 + TB - 1) / TB;
        hipMemsetAsync(d_ws, 0, (size_t)3 * n * sizeof(int), stream);
        k_deg<<<eb, TB, 0, stream>>>(dst, deg, E);
        k_init<<<ib, TB, 0, stream>>>(x, W, deg, dis, u, n);
        k_scatter<<<eb, TB, 0, stream>>>(src, dst, u, s1, E);
        k_update<<<nb, TB, 0, stream>>>(dis, s1, u, n);
        k_scatter<<<eb, TB, 0, stream>>>(src, dst, u, s2, E);
        k_final<<<nb, TB, 0, stream>>>(dis, s2, u, b, out, n);
    }
}

// Round 5
// 63.176 us; speedup vs baseline: 1.0086x; 1.0086x over previous
//
#include <hip/hip_runtime.h>

// SGC: out = A^K (x w) + b  (rank-1 projection first), A = D^-1/2 (Adj+I) D^-1/2, K=2.
// - Per-edge device atomics measured ~16.7 G/s (48 us/pass) -> replaced by chunk-binned
//   LDS-accumulated hops.
// - R4 lesson: 40us fills in rocprof are the harness's 268MB d_ws poison (outside dur_us);
//   graph dispatch overhead ~0.2us/kernel. Our kernels sum to the wall time.
// - R5 change: k_bin now counting-sorts records in LDS and writes each bucket run
//   contiguously (coalesced), replacing 800K scattered 4B global stores.

#define D_FEAT    128
#define CHUNK_LG  10
#define CHUNK     1024
#define NSLAB     16
#define RECS      7           // edges per thread in k_bin; block tile = RECS*256 = 1792
#define MAXC      64

__global__ void k_zero(int* __restrict__ cnt) {
    cnt[threadIdx.x] = 0;      // <<<1, 64>>>
}

// Bin edges into per-chunk buckets via LDS counting sort; coalesced bucket-run writes.
// binned record = (dst_local<<16) | src   (dst_local < 1024, src < 65536)
__global__ void k_bin(const int* __restrict__ src, const int* __restrict__ dst,
                      int E, int nchunks, int cap,
                      int* __restrict__ cnt, unsigned int* __restrict__ binned) {
    __shared__ int hist[MAXC], base[MAXC], cur[MAXC], gbase[MAXC];
    __shared__ unsigned int recs[RECS * 256];          // 7 KB
    int t = threadIdx.x;
    if (t < MAXC) hist[t] = 0;
    __syncthreads();

    int e0 = blockIdx.x * (RECS * 256);
    int nrec = E - e0; if (nrec > RECS * 256) nrec = RECS * 256;

    unsigned int rec[RECS]; int ch[RECS];
    #pragma unroll
    for (int k = 0; k < RECS; k++) {
        int e = e0 + k * 256 + t;
        if (e < E) {
            int s = src[e], d = dst[e];
            ch[k]  = d >> CHUNK_LG;                                    // 6 bits
            rec[k] = ((unsigned)ch[k] << 26) |
                     ((unsigned)(d & (CHUNK - 1)) << 16) | (unsigned)s;
            atomicAdd(&hist[ch[k]], 1);
        } else ch[k] = -1;
    }
    __syncthreads();

    // wave 0: inclusive shfl-scan over 64 buckets -> local exclusive base; device reserve
    if (t < 64) {
        int h = hist[t];
        int v = h;
        #pragma unroll
        for (int off = 1; off < 64; off <<= 1) {
            int w = __shfl_up(v, off);
            if (t >= off) v += w;
        }
        base[t]  = v - h;
        cur[t]   = v - h;
        gbase[t] = atomicAdd(&cnt[t], h);              // 64 device atomics per block
    }
    __syncthreads();

    // scatter records into LDS in bucket-sorted order
    #pragma unroll
    for (int k = 0; k < RECS; k++) {
        if (ch[k] >= 0) {
            int pos = atomicAdd(&cur[ch[k]], 1);
            recs[pos] = rec[k];
        }
    }
    __syncthreads();

    // coalesced write-out: consecutive j -> same bucket, consecutive slots
    for (int j = t; j < nrec; j += 256) {
        unsigned int r = recs[j];
        int c   = r >> 26;
        int off = j - base[c];
        int slot = gbase[c] + off;
        if (slot < cap) binned[(size_t)c * cap + slot] = r & 0x03FFFFFFu;
    }
}

// One chunk per c, NSLAB slabs; LDS fp32 accumulation; coalesced partial writes.
// MODE 0: count (value 1.0); MODE 1: sum val[src].
template <int MODE>
__global__ void k_hop(const unsigned int* __restrict__ binned, const int* __restrict__ cnt,
                      int cap, const float* __restrict__ val, float* __restrict__ partial) {
    __shared__ float acc[CHUNK];
    int c = blockIdx.x >> 4;          // / NSLAB
    int m = blockIdx.x & (NSLAB - 1);
    int t = threadIdx.x;
    #pragma unroll
    for (int k = 0; k < CHUNK / 256; k++) acc[t + k * 256] = 0.f;
    __syncthreads();
    int nc = cnt[c]; if (nc > cap) nc = cap;
    const unsigned int* bb = binned + (size_t)c * cap;
    for (int e = m * 256 + t; e < nc; e += NSLAB * 256) {
        unsigned int r = bb[e];
        float v = (MODE == 0) ? 1.0f : val[r & 0xFFFFu];
        atomicAdd(&acc[r >> 16], v);           // ds_add_f32
    }
    __syncthreads();
    float* pp = partial + ((size_t)(c * NSLAB + m) << CHUNK_LG);
    #pragma unroll
    for (int k = 0; k < CHUNK / 256; k++) pp[t + k * 256] = acc[t + k * 256];
}

// y[i] = x_i . w   (one wave per node, float2 loads)
__global__ void k_dot(const float* __restrict__ x, const float* __restrict__ W,
                      float* __restrict__ y, int n) {
    int wid  = (blockIdx.x * blockDim.x + threadIdx.x) >> 6;
    int lane = threadIdx.x & 63;
    if (wid >= n) return;
    const float2* xr = (const float2*)(x + (size_t)wid * D_FEAT);
    const float2* wr = (const float2*)W;
    float2 xv = xr[lane];
    float2 wv = wr[lane];
    float v = xv.x * wv.x + xv.y * wv.y;
    #pragma unroll
    for (int off = 32; off; off >>= 1) v += __shfl_xor(v, off);
    if (lane == 0) y[wid] = v;
}

// Sum the NSLAB partial slabs per node, then variant-specific epilogue.
// V0: dis=rsqrt(deg+1), u=dis*y      V1: u2=dis^2*(s+u)      V2: out=dis*(s+u2)+b
template <int V>
__global__ void k_reduce(const float* __restrict__ partial, int n,
                         const float* __restrict__ y, float* __restrict__ dis,
                         float* __restrict__ u, float* __restrict__ u2,
                         const float* __restrict__ b, float* __restrict__ out) {
    int i = blockIdx.x * blockDim.x + threadIdx.x;
    if (i >= n) return;
    int c = i >> CHUNK_LG, l = i & (CHUNK - 1);
    const float* pp = partial + ((size_t)(c * NSLAB) << CHUNK_LG) + l;
    float s = 0.f;
    #pragma unroll
    for (int m = 0; m < NSLAB; m++) s += pp[m << CHUNK_LG];
    if (V == 0) { float d = rsqrtf(s + 1.0f); dis[i] = d; u[i] = d * y[i]; }
    if (V == 1) { float d = dis[i]; u2[i] = d * d * (s + u[i]); }
    if (V == 2) { out[i] = dis[i] * (s + u2[i]) + b[0]; }
}

// ---------------- fallback (atomic) path, known-correct ----------------

__global__ void k_deg(const int* __restrict__ dst, int* __restrict__ deg, int E) {
    int e = blockIdx.x * blockDim.x + threadIdx.x;
    if (e < E) atomicAdd(&deg[dst[e]], 1);
}
__global__ void k_init(const float* __restrict__ x, const float* __restrict__ W,
                       const int* __restrict__ deg, float* __restrict__ dis,
                       float* __restrict__ u, int n) {
    int wid  = (blockIdx.x * blockDim.x + threadIdx.x) >> 6;
    int lane = threadIdx.x & 63;
    if (wid >= n) return;
    const float2* xr = (const float2*)(x + (size_t)wid * D_FEAT);
    const float2* wr = (const float2*)W;
    float2 xv = xr[lane];
    float2 wv = wr[lane];
    float v = xv.x * wv.x + xv.y * wv.y;
    #pragma unroll
    for (int off = 32; off; off >>= 1) v += __shfl_xor(v, off);
    if (lane == 0) { float di = rsqrtf((float)(deg[wid] + 1)); dis[wid] = di; u[wid] = di * v; }
}
__global__ void k_scatter(const int* __restrict__ src, const int* __restrict__ dst,
                          const float* __restrict__ u, float* __restrict__ s, int E) {
    int e = blockIdx.x * blockDim.x + threadIdx.x;
    if (e < E) unsafeAtomicAdd(&s[dst[e]], u[src[e]]);
}
__global__ void k_update(const float* __restrict__ dis, const float* __restrict__ s,
                         float* __restrict__ u, int n) {
    int i = blockIdx.x * blockDim.x + threadIdx.x;
    if (i < n) { float di = dis[i]; u[i] = di * di * (s[i] + u[i]); }
}
__global__ void k_final(const float* __restrict__ dis, const float* __restrict__ s,
                        const float* __restrict__ u, const float* __restrict__ b,
                        float* __restrict__ out, int n) {
    int i = blockIdx.x * blockDim.x + threadIdx.x;
    if (i < n) out[i] = dis[i] * (s[i] + u[i]) + b[0];
}

extern "C" void kernel_launch(void* const* d_in, const int* in_sizes, int n_in,
                              void* d_out, int out_size, void* d_ws, size_t ws_size,
                              hipStream_t stream) {
    const float* x  = (const float*)d_in[0];
    const int*   ei = (const int*)d_in[1];   // [2,E]; row0=src, row1=dst
    const float* W  = (const float*)d_in[2];
    const float* b  = (const float*)d_in[3];
    float* out = (float*)d_out;

    const int n = out_size;           // 50000
    const int E = in_sizes[1] / 2;    // 800000
    const int* src = ei;
    const int* dst = ei + E;

    const int TB = 256;
    const int C  = (n + CHUNK - 1) >> CHUNK_LG;                 // 49
    const int cap = (int)((long long)E * 5 / (4 * C)) + 512;    // ~25% headroom

    size_t need = 64 * 4 + (size_t)C * cap * 4 + (size_t)C * NSLAB * CHUNK * 4 + (size_t)4 * n * 4;

    if (n <= 65536 && C <= MAXC && ws_size >= need) {
        int*          cnt    = (int*)d_ws;
        unsigned int* binned = (unsigned int*)(cnt + 64);
        float*        part   = (float*)(binned + (size_t)C * cap);
        float*        y      = part + (size_t)C * NSLAB * CHUNK;
        float*        dis    = y + n;
        float*        u      = dis + n;
        float*        u2     = u + n;

        const int binBlocks = (E + RECS * 256 - 1) / (RECS * 256);
        const int hopBlocks = C * NSLAB;
        const int nb        = (n + TB - 1) / TB;
        const int dotBlocks = ((size_t)n * 64 + TB - 1) / TB;

        k_zero<<<1, 64, 0, stream>>>(cnt);
        k_bin<<<binBlocks, TB, 0, stream>>>(src, dst, E, C, cap, cnt, binned);
        k_dot<<<dotBlocks, TB, 0, stream>>>(x, W, y, n);

        k_hop<0><<<hopBlocks, TB, 0, stream>>>(binned, cnt, cap, y, part);       // degree
        k_reduce<0><<<nb, TB, 0, stream>>>(part, n, y, dis, u, u2, b, out);

        k_hop<1><<<hopBlocks, TB, 0, stream>>>(binned, cnt, cap, u, part);       // hop 1
        k_reduce<1><<<nb, TB, 0, stream>>>(part, n, y, dis, u, u2, b, out);

        k_hop<1><<<hopBlocks, TB, 0, stream>>>(binned, cnt, cap, u2, part);      // hop 2
        k_reduce<2><<<nb, TB, 0, stream>>>(part, n, y, dis, u, u2, b, out);
    } else {
        int*   deg = (int*)d_ws;
        float* s1  = (float*)d_ws + n;
        float* s2  = s1 + n;
        float* dis = s2 + n;
        float* u   = dis + n;
        const int eb = (E + TB - 1) / TB;
        const int nb = (n + TB - 1) / TB;
        const int ib = ((size_t)n * 64 + TB - 1) / TB;
        hipMemsetAsync(d_ws, 0, (size_t)3 * n * sizeof(int), stream);
        k_deg<<<eb, TB, 0, stream>>>(dst, deg, E);
        k_init<<<ib, TB, 0, stream>>>(x, W, deg, dis, u, n);
        k_scatter<<<eb, TB, 0, stream>>>(src, dst, u, s1, E);
        k_update<<<nb, TB, 0, stream>>>(dis, s1, u, n);
        k_scatter<<<eb, TB, 0, stream>>>(src, dst, u, s2, E);
        k_final<<<nb, TB, 0, stream>>>(dis, s2, u, b, out, n);
    }
}